// Round 1
// baseline (620.157 us; speedup 1.0000x reference)
//
#include <hip/hip_runtime.h>
#include <hip/hip_bf16.h>
#include <stdint.h>

#define T_TOK 4096
#define E_EXP 8
#define D_DIM 1024
#define F_DIM 4096
#define K_TOP 2
#define CAPC  1024

typedef __attribute__((ext_vector_type(8))) short short8;
typedef __attribute__((ext_vector_type(4))) float f32x4;
typedef __attribute__((ext_vector_type(4))) unsigned short u16x4;

static __device__ __forceinline__ unsigned short f2bf(float f) {
  union { float f; unsigned u; } v; v.f = f;
  unsigned r = v.u + 0x7fffu + ((v.u >> 16) & 1u);
  return (unsigned short)(r >> 16);
}

static __device__ __forceinline__ void gload_lds16(const void* g, void* l) {
  __builtin_amdgcn_global_load_lds(
      (const __attribute__((address_space(1))) unsigned int*)g,
      (__attribute__((address_space(3))) unsigned int*)l, 16, 0, 0);
}

// ---------------------------------------------------------------- routing ---
__global__ void zero_int_kernel(int* p, int n) {
  int i = blockIdx.x * 256 + threadIdx.x;
  if (i < n) p[i] = 0;
}

// One block per expert. Full descending bitonic sort of 4096 packed keys:
// key = (weight_bits << 32) | (T-1-t)  -> ties prefer lower token index,
// matching jax.lax.top_k stability. Invalid (unrouted) tokens get key 0.
__global__ __launch_bounds__(1024) void select_kernel(
    const float* __restrict__ rw,   // (T,E) route_weight (0 where unrouted)
    int* __restrict__ sel_idx,      // (E,CAP) token id or -1
    float* __restrict__ sel_w,      // (E,CAP)
    int* __restrict__ inv_cnt,      // (T)
    int* __restrict__ inv_ec,       // (T,K) e*CAP+c
    float* __restrict__ inv_w)      // (T,K)
{
  __shared__ unsigned long long keys[T_TOK];
  const int e = blockIdx.x;
  for (int t = threadIdx.x; t < T_TOK; t += 1024) {
    float w = rw[(size_t)t * E_EXP + e];
    unsigned wb = __float_as_uint(w);
    keys[t] = (w > 0.f)
        ? ((((unsigned long long)wb) << 32) | (unsigned)(T_TOK - 1 - t))
        : 0ull;
  }
  for (int k = 2; k <= T_TOK; k <<= 1) {
    for (int j = k >> 1; j > 0; j >>= 1) {
      __syncthreads();
      for (int i = threadIdx.x; i < T_TOK; i += 1024) {
        int ixj = i ^ j;
        if (ixj > i) {
          unsigned long long a = keys[i], b = keys[ixj];
          bool sw = ((i & k) == 0) ? (a < b) : (a > b);  // descending sort
          if (sw) { keys[i] = b; keys[ixj] = a; }
        }
      }
    }
  }
  __syncthreads();
  for (int c = threadIdx.x; c < CAPC; c += 1024) {
    unsigned long long key = keys[c];
    int t = -1; float w = 0.f;
    if ((key >> 32) != 0ull) {
      t = T_TOK - 1 - (int)(key & 0xffffffffu);
      w = __uint_as_float((unsigned)(key >> 32));
    }
    sel_idx[e * CAPC + c] = t;
    sel_w[e * CAPC + c] = w;
    if (t >= 0) {
      int p = atomicAdd(&inv_cnt[t], 1);
      inv_ec[t * K_TOP + p] = e * CAPC + c;
      inv_w[t * K_TOP + p] = w;
    }
  }
}

// ---------------------------------------------------------------- prepass ---
__global__ void convert_x_kernel(const float* __restrict__ x,
                                 unsigned short* __restrict__ xb, int n4) {
  int i = blockIdx.x * 256 + threadIdx.x;
  if (i >= n4) return;
  f32x4 v = ((const f32x4*)x)[i];
  u16x4 o = { f2bf(v.x), f2bf(v.y), f2bf(v.z), f2bf(v.w) };
  ((u16x4*)xb)[i] = o;
}

// in: (E,R,C) f32 row-major  ->  out: (E,C,R) bf16. 64x64 tiles through LDS.
__global__ __launch_bounds__(256) void transpose_bf16_kernel(
    const float* __restrict__ in, unsigned short* __restrict__ out,
    int R, int C)
{
  __shared__ unsigned short tile[64][68];  // +4 pad breaks bank conflicts
  const int e = blockIdx.z;
  const float* inp = in + (size_t)e * R * C;
  unsigned short* outp = out + (size_t)e * R * C;
  const int c0 = blockIdx.x * 64, r0 = blockIdx.y * 64;
  const int q4 = (threadIdx.x & 15) * 4;
  const int tr = threadIdx.x >> 4;  // 0..15
  for (int rr = tr; rr < 64; rr += 16) {
    f32x4 v = *(const f32x4*)(inp + (size_t)(r0 + rr) * C + c0 + q4);
    tile[rr][q4 + 0] = f2bf(v.x);
    tile[rr][q4 + 1] = f2bf(v.y);
    tile[rr][q4 + 2] = f2bf(v.z);
    tile[rr][q4 + 3] = f2bf(v.w);
  }
  __syncthreads();
  for (int cc = tr; cc < 64; cc += 16) {
    u16x4 o = { tile[q4 + 0][cc], tile[q4 + 1][cc],
                tile[q4 + 2][cc], tile[q4 + 3][cc] };
    *(u16x4*)(outp + (size_t)(c0 + cc) * R + r0 + q4) = o;
  }
}

// ------------------------------------------------------------------ GEMMs ---
// m97-pattern: BM=BN=128, BK=32, 256 threads = 4 waves (2x2 of 64x64),
// 16x16x32 bf16 MFMA, global_load_lds width-16 staging, both operands
// k-contiguous. A rows for GEMM1 gathered via sel_idx.

__global__ __launch_bounds__(256) void gemm1_kernel(
    const unsigned short* __restrict__ xb,     // (T,D) bf16
    const int* __restrict__ sel_idx,           // (E,CAP)
    const unsigned short* __restrict__ w1t,    // (E,F,D) bf16
    const float* __restrict__ b1,              // (E,F)
    unsigned short* __restrict__ H)            // (E,CAP,F) bf16
{
  __shared__ __align__(16) unsigned short Asm[128 * 32];
  __shared__ __align__(16) unsigned short Bsm[128 * 32];
  const int e = blockIdx.z;
  const int m0 = blockIdx.y * 128;
  const int n0 = blockIdx.x * 128;
  const int tid = threadIdx.x;
  const int lane = tid & 63, wv = tid >> 6;
  const int wm = (wv >> 1) * 64, wn = (wv & 1) * 64;
  const int lrow = lane & 15, quad = lane >> 4;

  const int r = tid >> 2, seg = tid & 3;
  int t0 = sel_idx[e * CAPC + m0 + r];      if (t0 < 0) t0 = 0;
  int t1 = sel_idx[e * CAPC + m0 + 64 + r]; if (t1 < 0) t1 = 0;
  const unsigned short* gA0 = xb + (size_t)t0 * D_DIM + seg * 8;
  const unsigned short* gA1 = xb + (size_t)t1 * D_DIM + seg * 8;
  const unsigned short* w1e = w1t + (size_t)e * F_DIM * D_DIM;
  const unsigned short* gB0 = w1e + (size_t)(n0 + r) * D_DIM + seg * 8;
  const unsigned short* gB1 = w1e + (size_t)(n0 + 64 + r) * D_DIM + seg * 8;
  char* lA0 = (char*)Asm + (size_t)(wv * 64) * 16;
  char* lA1 = (char*)Asm + (size_t)(256 + wv * 64) * 16;
  char* lB0 = (char*)Bsm + (size_t)(wv * 64) * 16;
  char* lB1 = (char*)Bsm + (size_t)(256 + wv * 64) * 16;

  f32x4 acc[4][4];
#pragma unroll
  for (int a = 0; a < 4; ++a)
#pragma unroll
    for (int b = 0; b < 4; ++b) acc[a][b] = (f32x4){0.f, 0.f, 0.f, 0.f};

  for (int k0 = 0; k0 < D_DIM; k0 += 32) {
    gload_lds16(gA0, lA0);
    gload_lds16(gA1, lA1);
    gload_lds16(gB0, lB0);
    gload_lds16(gB1, lB1);
    gA0 += 32; gA1 += 32; gB0 += 32; gB1 += 32;
    __syncthreads();
    short8 af[4], bf[4];
#pragma unroll
    for (int mt = 0; mt < 4; ++mt)
      af[mt] = *(const short8*)(Asm + (wm + mt * 16 + lrow) * 32 + quad * 8);
#pragma unroll
    for (int nt = 0; nt < 4; ++nt)
      bf[nt] = *(const short8*)(Bsm + (wn + nt * 16 + lrow) * 32 + quad * 8);
#pragma unroll
    for (int mt = 0; mt < 4; ++mt)
#pragma unroll
      for (int nt = 0; nt < 4; ++nt)
        acc[mt][nt] = __builtin_amdgcn_mfma_f32_16x16x32_bf16(
            af[mt], bf[nt], acc[mt][nt], 0, 0, 0);
    __syncthreads();
  }

  const float* b1e = b1 + e * F_DIM;
#pragma unroll
  for (int nt = 0; nt < 4; ++nt) {
    const int col = n0 + wn + nt * 16 + lrow;
    const float bias = b1e[col];
#pragma unroll
    for (int mt = 0; mt < 4; ++mt) {
      const int rowb = m0 + wm + mt * 16 + quad * 4;
#pragma unroll
      for (int i = 0; i < 4; ++i) {
        float v = acc[mt][nt][i] + bias;
        float u = 0.7978845608028654f * (v + 0.044715f * v * v * v);
        float th = 1.f - 2.f / (1.f + __expf(2.f * u));  // tanh(u)
        float hv = 0.5f * v * (1.f + th);
        H[((size_t)e * CAPC + rowb + i) * F_DIM + col] = f2bf(hv);
      }
    }
  }
}

__global__ __launch_bounds__(256) void gemm2_kernel(
    const unsigned short* __restrict__ H,      // (E,CAP,F) bf16
    const unsigned short* __restrict__ w2t,    // (E,D,F) bf16
    const float* __restrict__ b2,              // (E,D)
    float* __restrict__ Out)                   // (E,CAP,D) f32
{
  __shared__ __align__(16) unsigned short Asm[128 * 32];
  __shared__ __align__(16) unsigned short Bsm[128 * 32];
  const int e = blockIdx.z;
  const int m0 = blockIdx.y * 128;
  const int n0 = blockIdx.x * 128;
  const int tid = threadIdx.x;
  const int lane = tid & 63, wv = tid >> 6;
  const int wm = (wv >> 1) * 64, wn = (wv & 1) * 64;
  const int lrow = lane & 15, quad = lane >> 4;

  const int r = tid >> 2, seg = tid & 3;
  const unsigned short* He = H + (size_t)e * CAPC * F_DIM;
  const unsigned short* gA0 = He + (size_t)(m0 + r) * F_DIM + seg * 8;
  const unsigned short* gA1 = He + (size_t)(m0 + 64 + r) * F_DIM + seg * 8;
  const unsigned short* w2e = w2t + (size_t)e * D_DIM * F_DIM;
  const unsigned short* gB0 = w2e + (size_t)(n0 + r) * F_DIM + seg * 8;
  const unsigned short* gB1 = w2e + (size_t)(n0 + 64 + r) * F_DIM + seg * 8;
  char* lA0 = (char*)Asm + (size_t)(wv * 64) * 16;
  char* lA1 = (char*)Asm + (size_t)(256 + wv * 64) * 16;
  char* lB0 = (char*)Bsm + (size_t)(wv * 64) * 16;
  char* lB1 = (char*)Bsm + (size_t)(256 + wv * 64) * 16;

  f32x4 acc[4][4];
#pragma unroll
  for (int a = 0; a < 4; ++a)
#pragma unroll
    for (int b = 0; b < 4; ++b) acc[a][b] = (f32x4){0.f, 0.f, 0.f, 0.f};

  for (int k0 = 0; k0 < F_DIM; k0 += 32) {
    gload_lds16(gA0, lA0);
    gload_lds16(gA1, lA1);
    gload_lds16(gB0, lB0);
    gload_lds16(gB1, lB1);
    gA0 += 32; gA1 += 32; gB0 += 32; gB1 += 32;
    __syncthreads();
    short8 af[4], bf[4];
#pragma unroll
    for (int mt = 0; mt < 4; ++mt)
      af[mt] = *(const short8*)(Asm + (wm + mt * 16 + lrow) * 32 + quad * 8);
#pragma unroll
    for (int nt = 0; nt < 4; ++nt)
      bf[nt] = *(const short8*)(Bsm + (wn + nt * 16 + lrow) * 32 + quad * 8);
#pragma unroll
    for (int mt = 0; mt < 4; ++mt)
#pragma unroll
      for (int nt = 0; nt < 4; ++nt)
        acc[mt][nt] = __builtin_amdgcn_mfma_f32_16x16x32_bf16(
            af[mt], bf[nt], acc[mt][nt], 0, 0, 0);
    __syncthreads();
  }

  const float* b2e = b2 + e * D_DIM;
#pragma unroll
  for (int nt = 0; nt < 4; ++nt) {
    const int col = n0 + wn + nt * 16 + lrow;
    const float bias = b2e[col];
#pragma unroll
    for (int mt = 0; mt < 4; ++mt) {
      const int rowb = m0 + wm + mt * 16 + quad * 4;
#pragma unroll
      for (int i = 0; i < 4; ++i) {
        Out[((size_t)e * CAPC + rowb + i) * D_DIM + col] = acc[mt][nt][i] + bias;
      }
    }
  }
}

// ---------------------------------------------------------------- combine ---
__global__ __launch_bounds__(256) void combine_kernel(
    const float* __restrict__ Out, const int* __restrict__ inv_cnt,
    const int* __restrict__ inv_ec, const float* __restrict__ inv_w,
    float* __restrict__ y)
{
  const int t = blockIdx.x;
  const int cnt = inv_cnt[t];
  f32x4 s = {0.f, 0.f, 0.f, 0.f};
  const int d4 = threadIdx.x;  // 256 threads x float4 = 1024 = D
  for (int p = 0; p < cnt; ++p) {
    const int ec = inv_ec[t * K_TOP + p];
    const float w = inv_w[t * K_TOP + p];
    f32x4 v = ((const f32x4*)(Out + (size_t)ec * D_DIM))[d4];
    s += v * w;
  }
  ((f32x4*)(y + (size_t)t * D_DIM))[d4] = s;
}

// ----------------------------------------------------------------- launch ---
extern "C" void kernel_launch(void* const* d_in, const int* in_sizes, int n_in,
                              void* d_out, int out_size, void* d_ws, size_t ws_size,
                              hipStream_t stream) {
  (void)in_sizes; (void)n_in; (void)out_size; (void)ws_size;
  const float* x  = (const float*)d_in[0];
  // d_in[1] = route_mask (bool) -- unused; mask == (route_weight > 0)
  const float* rw = (const float*)d_in[2];
  const float* w1 = (const float*)d_in[3];
  const float* b1 = (const float*)d_in[4];
  const float* w2 = (const float*)d_in[5];
  const float* b2 = (const float*)d_in[6];
  float* y = (float*)d_out;

  char* ws = (char*)d_ws;
  size_t off = 0;
  auto alloc = [&](size_t bytes) {
    void* p = ws + off;
    off += (bytes + 255) & ~(size_t)255;
    return p;
  };
  unsigned short* xb  = (unsigned short*)alloc((size_t)T_TOK * D_DIM * 2);
  unsigned short* w1t = (unsigned short*)alloc((size_t)E_EXP * F_DIM * D_DIM * 2);
  unsigned short* w2t = (unsigned short*)alloc((size_t)E_EXP * D_DIM * F_DIM * 2);
  unsigned short* H   = (unsigned short*)alloc((size_t)E_EXP * CAPC * F_DIM * 2);
  float* Out          = (float*)alloc((size_t)E_EXP * CAPC * D_DIM * 4);
  int* sel_idx        = (int*)alloc((size_t)E_EXP * CAPC * 4);
  float* sel_w        = (float*)alloc((size_t)E_EXP * CAPC * 4);
  int* inv_cnt        = (int*)alloc((size_t)T_TOK * 4);
  int* inv_ec         = (int*)alloc((size_t)T_TOK * K_TOP * 4);
  float* inv_w        = (float*)alloc((size_t)T_TOK * K_TOP * 4);

  // routing
  zero_int_kernel<<<(T_TOK + 255) / 256, 256, 0, stream>>>(inv_cnt, T_TOK);
  select_kernel<<<E_EXP, 1024, 0, stream>>>(rw, sel_idx, sel_w, inv_cnt, inv_ec, inv_w);

  // prepass: bf16 convert + weight transposes
  convert_x_kernel<<<(T_TOK * D_DIM / 4 + 255) / 256, 256, 0, stream>>>(
      x, xb, T_TOK * D_DIM / 4);
  transpose_bf16_kernel<<<dim3(F_DIM / 64, D_DIM / 64, E_EXP), 256, 0, stream>>>(
      w1, w1t, D_DIM, F_DIM);  // (E,D,F) -> (E,F,D)
  transpose_bf16_kernel<<<dim3(D_DIM / 64, F_DIM / 64, E_EXP), 256, 0, stream>>>(
      w2, w2t, F_DIM, D_DIM);  // (E,F,D) -> (E,D,F)

  // expert MLP
  gemm1_kernel<<<dim3(F_DIM / 128, CAPC / 128, E_EXP), 256, 0, stream>>>(
      xb, sel_idx, w1t, b1, H);
  gemm2_kernel<<<dim3(D_DIM / 128, CAPC / 128, E_EXP), 256, 0, stream>>>(
      H, w2t, b2, Out);

  // weighted combine back to token order (also zeroes dropped tokens)
  combine_kernel<<<T_TOK, 256, 0, stream>>>(Out, inv_cnt, inv_ec, inv_w, y);
}

// Round 2
// 595.609 us; speedup vs baseline: 1.0412x; 1.0412x over previous
//
#include <hip/hip_runtime.h>
#include <hip/hip_bf16.h>
#include <stdint.h>

#define T_TOK 4096
#define E_EXP 8
#define D_DIM 1024
#define F_DIM 4096
#define K_TOP 2
#define CAPC  1024

typedef __attribute__((ext_vector_type(8))) short short8;
typedef __attribute__((ext_vector_type(4))) float f32x4;
typedef __attribute__((ext_vector_type(4))) unsigned short u16x4;

static __device__ __forceinline__ unsigned short f2bf(float f) {
  union { float f; unsigned u; } v; v.f = f;
  unsigned r = v.u + 0x7fffu + ((v.u >> 16) & 1u);
  return (unsigned short)(r >> 16);
}

static __device__ __forceinline__ void gload_lds16(const void* g, void* l) {
  __builtin_amdgcn_global_load_lds(
      (const __attribute__((address_space(1))) unsigned int*)g,
      (__attribute__((address_space(3))) unsigned int*)l, 16, 0, 0);
}

// ---------------------------------------------------------------- routing ---
__global__ void zero_int_kernel(int* p, int n) {
  int i = blockIdx.x * 256 + threadIdx.x;
  if (i < n) p[i] = 0;
}

// One block per expert. Full descending bitonic sort of 4096 packed keys:
// key = (weight_bits << 32) | (T-1-t)  -> ties prefer lower token index,
// matching jax.lax.top_k stability. Invalid (unrouted) tokens get key 0.
__global__ __launch_bounds__(1024) void select_kernel(
    const float* __restrict__ rw,   // (T,E) route_weight (0 where unrouted)
    int* __restrict__ sel_idx,      // (E,CAP) token id or -1
    int* __restrict__ inv_cnt,      // (T)
    int* __restrict__ inv_ec,       // (T,K) e*CAP+c
    float* __restrict__ inv_w)      // (T,K)
{
  __shared__ unsigned long long keys[T_TOK];
  const int e = blockIdx.x;
  for (int t = threadIdx.x; t < T_TOK; t += 1024) {
    float w = rw[(size_t)t * E_EXP + e];
    unsigned wb = __float_as_uint(w);
    keys[t] = (w > 0.f)
        ? ((((unsigned long long)wb) << 32) | (unsigned)(T_TOK - 1 - t))
        : 0ull;
  }
  for (int k = 2; k <= T_TOK; k <<= 1) {
    for (int j = k >> 1; j > 0; j >>= 1) {
      __syncthreads();
      for (int i = threadIdx.x; i < T_TOK; i += 1024) {
        int ixj = i ^ j;
        if (ixj > i) {
          unsigned long long a = keys[i], b = keys[ixj];
          bool sw = ((i & k) == 0) ? (a < b) : (a > b);  // descending sort
          if (sw) { keys[i] = b; keys[ixj] = a; }
        }
      }
    }
  }
  __syncthreads();
  for (int c = threadIdx.x; c < CAPC; c += 1024) {
    unsigned long long key = keys[c];
    int t = -1; float w = 0.f;
    if ((key >> 32) != 0ull) {
      t = T_TOK - 1 - (int)(key & 0xffffffffu);
      w = __uint_as_float((unsigned)(key >> 32));
    }
    sel_idx[e * CAPC + c] = t;
    if (t >= 0) {
      int p = atomicAdd(&inv_cnt[t], 1);
      inv_ec[t * K_TOP + p] = e * CAPC + c;
      inv_w[t * K_TOP + p] = w;
    }
  }
}

// ---------------------------------------------------------------- prepass ---
__global__ void convert_x_kernel(const float* __restrict__ x,
                                 unsigned short* __restrict__ xb, int n4) {
  int i = blockIdx.x * 256 + threadIdx.x;
  if (i >= n4) return;
  f32x4 v = ((const f32x4*)x)[i];
  u16x4 o = { f2bf(v.x), f2bf(v.y), f2bf(v.z), f2bf(v.w) };
  ((u16x4*)xb)[i] = o;
}

// in: (E,R,C) f32 row-major  ->  out: (E,C,R) bf16. 64x64 tiles through LDS.
__global__ __launch_bounds__(256) void transpose_bf16_kernel(
    const float* __restrict__ in, unsigned short* __restrict__ out,
    int R, int C)
{
  __shared__ unsigned short tile[64][68];  // +4 pad breaks bank conflicts
  const int e = blockIdx.z;
  const float* inp = in + (size_t)e * R * C;
  unsigned short* outp = out + (size_t)e * R * C;
  const int c0 = blockIdx.x * 64, r0 = blockIdx.y * 64;
  const int q4 = (threadIdx.x & 15) * 4;
  const int tr = threadIdx.x >> 4;  // 0..15
  for (int rr = tr; rr < 64; rr += 16) {
    f32x4 v = *(const f32x4*)(inp + (size_t)(r0 + rr) * C + c0 + q4);
    tile[rr][q4 + 0] = f2bf(v.x);
    tile[rr][q4 + 1] = f2bf(v.y);
    tile[rr][q4 + 2] = f2bf(v.z);
    tile[rr][q4 + 3] = f2bf(v.w);
  }
  __syncthreads();
  for (int cc = tr; cc < 64; cc += 16) {
    u16x4 o = { tile[q4 + 0][cc], tile[q4 + 1][cc],
                tile[q4 + 2][cc], tile[q4 + 3][cc] };
    *(u16x4*)(outp + (size_t)(c0 + cc) * R + r0 + q4) = o;
  }
}

// ------------------------------------------------------------------ GEMMs ---
// BM=BN=128, BK=64, 256 threads = 4 waves (2x2 of 64x64), 16x16x32 bf16 MFMA,
// global_load_lds width-16 staging. XOR chunk swizzle (chunk ^= row&7) makes
// ds_read_b128 fragment reads bank-conflict-free (8 lanes span all 32 banks).

__global__ __launch_bounds__(256, 3) void gemm1_kernel(
    const unsigned short* __restrict__ xb,     // (T,D) bf16
    const int* __restrict__ sel_idx,           // (E,CAP)
    const unsigned short* __restrict__ w1t,    // (E,F,D) bf16
    const float* __restrict__ b1,              // (E,F)
    unsigned short* __restrict__ H)            // (E,CAP,F) bf16
{
  __shared__ __align__(16) unsigned short Asm[128 * 64];
  __shared__ __align__(16) unsigned short Bsm[128 * 64];
  const int e = blockIdx.z;
  const int m0 = blockIdx.y * 128;
  const int n0 = blockIdx.x * 128;
  const int tid = threadIdx.x;
  const int lane = tid & 63, wv = tid >> 6;
  const int wm = (wv >> 1) * 64, wn = (wv & 1) * 64;
  const int lrow = lane & 15, quad = lane >> 4;

  // staging: thread (rbase+it*32, seg) DMAs swizzled chunk cs of its row
  const int rbase = tid >> 3, seg = tid & 7;
  const int cs = seg ^ (rbase & 7);
  const unsigned short* gA[4];
  const unsigned short* gB[4];
  char* lA[4];
  char* lB[4];
  const unsigned short* w1e = w1t + (size_t)e * F_DIM * D_DIM;
#pragma unroll
  for (int it = 0; it < 4; ++it) {
    const int row = rbase + it * 32;
    int t = sel_idx[e * CAPC + m0 + row];
    if (t < 0) t = 0;
    gA[it] = xb + (size_t)t * D_DIM + cs * 8;
    gB[it] = w1e + (size_t)(n0 + row) * D_DIM + cs * 8;
    lA[it] = (char*)Asm + it * 4096 + wv * 1024;
    lB[it] = (char*)Bsm + it * 4096 + wv * 1024;
  }

  f32x4 acc[4][4];
#pragma unroll
  for (int a = 0; a < 4; ++a)
#pragma unroll
    for (int b = 0; b < 4; ++b) acc[a][b] = (f32x4){0.f, 0.f, 0.f, 0.f};

  const int sw = lrow & 7;
  for (int k0 = 0; k0 < D_DIM; k0 += 64) {
#pragma unroll
    for (int it = 0; it < 4; ++it) { gload_lds16(gA[it], lA[it]); gA[it] += 64; }
#pragma unroll
    for (int it = 0; it < 4; ++it) { gload_lds16(gB[it], lB[it]); gB[it] += 64; }
    __syncthreads();
#pragma unroll
    for (int h = 0; h < 2; ++h) {
      short8 af[4], bf[4];
#pragma unroll
      for (int mt = 0; mt < 4; ++mt)
        af[mt] = *(const short8*)(Asm + (wm + mt * 16 + lrow) * 64 +
                                  (((h << 2) + quad) ^ sw) * 8);
#pragma unroll
      for (int nt = 0; nt < 4; ++nt)
        bf[nt] = *(const short8*)(Bsm + (wn + nt * 16 + lrow) * 64 +
                                  (((h << 2) + quad) ^ sw) * 8);
#pragma unroll
      for (int mt = 0; mt < 4; ++mt)
#pragma unroll
        for (int nt = 0; nt < 4; ++nt)
          acc[mt][nt] = __builtin_amdgcn_mfma_f32_16x16x32_bf16(
              af[mt], bf[nt], acc[mt][nt], 0, 0, 0);
    }
    __syncthreads();
  }

  const float* b1e = b1 + e * F_DIM;
#pragma unroll
  for (int nt = 0; nt < 4; ++nt) {
    const int col = n0 + wn + nt * 16 + lrow;
    const float bias = b1e[col];
#pragma unroll
    for (int mt = 0; mt < 4; ++mt) {
      const int rowb = m0 + wm + mt * 16 + quad * 4;
#pragma unroll
      for (int i = 0; i < 4; ++i) {
        float v = acc[mt][nt][i] + bias;
        float u = 0.7978845608028654f * (v + 0.044715f * v * v * v);
        float th = 1.f - 2.f / (1.f + __expf(2.f * u));  // tanh(u)
        float hv = 0.5f * v * (1.f + th);
        H[((size_t)e * CAPC + rowb + i) * F_DIM + col] = f2bf(hv);
      }
    }
  }
}

// split-K=2: blockIdx.z = e + 8*ks; partial sums to P[ks]; bias in ks==0.
__global__ __launch_bounds__(256, 3) void gemm2_kernel(
    const unsigned short* __restrict__ H,      // (E,CAP,F) bf16
    const unsigned short* __restrict__ w2t,    // (E,D,F) bf16
    const float* __restrict__ b2,              // (E,D)
    float* __restrict__ P)                     // (2,E,CAP,D) f32 partials
{
  __shared__ __align__(16) unsigned short Asm[128 * 64];
  __shared__ __align__(16) unsigned short Bsm[128 * 64];
  const int e = blockIdx.z & 7;
  const int ks = blockIdx.z >> 3;
  const int m0 = blockIdx.y * 128;
  const int n0 = blockIdx.x * 128;
  const int kbase = ks * (F_DIM / 2);
  const int tid = threadIdx.x;
  const int lane = tid & 63, wv = tid >> 6;
  const int wm = (wv >> 1) * 64, wn = (wv & 1) * 64;
  const int lrow = lane & 15, quad = lane >> 4;

  const int rbase = tid >> 3, seg = tid & 7;
  const int cs = seg ^ (rbase & 7);
  const unsigned short* gA[4];
  const unsigned short* gB[4];
  char* lA[4];
  char* lB[4];
  const unsigned short* He = H + (size_t)e * CAPC * F_DIM;
  const unsigned short* w2e = w2t + (size_t)e * D_DIM * F_DIM;
#pragma unroll
  for (int it = 0; it < 4; ++it) {
    const int row = rbase + it * 32;
    gA[it] = He + (size_t)(m0 + row) * F_DIM + kbase + cs * 8;
    gB[it] = w2e + (size_t)(n0 + row) * F_DIM + kbase + cs * 8;
    lA[it] = (char*)Asm + it * 4096 + wv * 1024;
    lB[it] = (char*)Bsm + it * 4096 + wv * 1024;
  }

  f32x4 acc[4][4];
#pragma unroll
  for (int a = 0; a < 4; ++a)
#pragma unroll
    for (int b = 0; b < 4; ++b) acc[a][b] = (f32x4){0.f, 0.f, 0.f, 0.f};

  const int sw = lrow & 7;
  for (int k0 = 0; k0 < F_DIM / 2; k0 += 64) {
#pragma unroll
    for (int it = 0; it < 4; ++it) { gload_lds16(gA[it], lA[it]); gA[it] += 64; }
#pragma unroll
    for (int it = 0; it < 4; ++it) { gload_lds16(gB[it], lB[it]); gB[it] += 64; }
    __syncthreads();
#pragma unroll
    for (int h = 0; h < 2; ++h) {
      short8 af[4], bf[4];
#pragma unroll
      for (int mt = 0; mt < 4; ++mt)
        af[mt] = *(const short8*)(Asm + (wm + mt * 16 + lrow) * 64 +
                                  (((h << 2) + quad) ^ sw) * 8);
#pragma unroll
      for (int nt = 0; nt < 4; ++nt)
        bf[nt] = *(const short8*)(Bsm + (wn + nt * 16 + lrow) * 64 +
                                  (((h << 2) + quad) ^ sw) * 8);
#pragma unroll
      for (int mt = 0; mt < 4; ++mt)
#pragma unroll
        for (int nt = 0; nt < 4; ++nt)
          acc[mt][nt] = __builtin_amdgcn_mfma_f32_16x16x32_bf16(
              af[mt], bf[nt], acc[mt][nt], 0, 0, 0);
    }
    __syncthreads();
  }

  const float* b2e = b2 + e * D_DIM;
  float* Pk = P + (size_t)ks * E_EXP * CAPC * D_DIM;
#pragma unroll
  for (int nt = 0; nt < 4; ++nt) {
    const int col = n0 + wn + nt * 16 + lrow;
    const float bias = (ks == 0) ? b2e[col] : 0.f;
#pragma unroll
    for (int mt = 0; mt < 4; ++mt) {
      const int rowb = m0 + wm + mt * 16 + quad * 4;
#pragma unroll
      for (int i = 0; i < 4; ++i) {
        Pk[((size_t)e * CAPC + rowb + i) * D_DIM + col] = acc[mt][nt][i] + bias;
      }
    }
  }
}

// ---------------------------------------------------------------- combine ---
__global__ __launch_bounds__(256) void combine_kernel(
    const float* __restrict__ P, const int* __restrict__ inv_cnt,
    const int* __restrict__ inv_ec, const float* __restrict__ inv_w,
    float* __restrict__ y)
{
  const int t = blockIdx.x;
  const int cnt = inv_cnt[t];
  f32x4 s = {0.f, 0.f, 0.f, 0.f};
  const int d4 = threadIdx.x;  // 256 threads x float4 = 1024 = D
  const size_t half = (size_t)E_EXP * CAPC * D_DIM;
  for (int p = 0; p < cnt; ++p) {
    const int ec = inv_ec[t * K_TOP + p];
    const float w = inv_w[t * K_TOP + p];
    f32x4 v0 = ((const f32x4*)(P + (size_t)ec * D_DIM))[d4];
    f32x4 v1 = ((const f32x4*)(P + half + (size_t)ec * D_DIM))[d4];
    s += (v0 + v1) * w;
  }
  ((f32x4*)(y + (size_t)t * D_DIM))[d4] = s;
}

// ----------------------------------------------------------------- launch ---
extern "C" void kernel_launch(void* const* d_in, const int* in_sizes, int n_in,
                              void* d_out, int out_size, void* d_ws, size_t ws_size,
                              hipStream_t stream) {
  (void)in_sizes; (void)n_in; (void)out_size; (void)ws_size;
  const float* x  = (const float*)d_in[0];
  // d_in[1] = route_mask (bool) -- unused; mask == (route_weight > 0)
  const float* rw = (const float*)d_in[2];
  const float* w1 = (const float*)d_in[3];
  const float* b1 = (const float*)d_in[4];
  const float* w2 = (const float*)d_in[5];
  const float* b2 = (const float*)d_in[6];
  float* y = (float*)d_out;

  char* ws = (char*)d_ws;
  size_t off = 0;
  auto alloc = [&](size_t bytes) {
    void* p = ws + off;
    off += (bytes + 255) & ~(size_t)255;
    return p;
  };
  unsigned short* xb  = (unsigned short*)alloc((size_t)T_TOK * D_DIM * 2);
  unsigned short* w1t = (unsigned short*)alloc((size_t)E_EXP * F_DIM * D_DIM * 2);
  unsigned short* w2t = (unsigned short*)alloc((size_t)E_EXP * D_DIM * F_DIM * 2);
  unsigned short* H   = (unsigned short*)alloc((size_t)E_EXP * CAPC * F_DIM * 2);
  float* P            = (float*)alloc((size_t)2 * E_EXP * CAPC * D_DIM * 4);
  int* sel_idx        = (int*)alloc((size_t)E_EXP * CAPC * 4);
  int* inv_cnt        = (int*)alloc((size_t)T_TOK * 4);
  int* inv_ec         = (int*)alloc((size_t)T_TOK * K_TOP * 4);
  float* inv_w        = (float*)alloc((size_t)T_TOK * K_TOP * 4);

  // routing
  zero_int_kernel<<<(T_TOK + 255) / 256, 256, 0, stream>>>(inv_cnt, T_TOK);
  select_kernel<<<E_EXP, 1024, 0, stream>>>(rw, sel_idx, inv_cnt, inv_ec, inv_w);

  // prepass: bf16 convert + weight transposes
  convert_x_kernel<<<(T_TOK * D_DIM / 4 + 255) / 256, 256, 0, stream>>>(
      x, xb, T_TOK * D_DIM / 4);
  transpose_bf16_kernel<<<dim3(F_DIM / 64, D_DIM / 64, E_EXP), 256, 0, stream>>>(
      w1, w1t, D_DIM, F_DIM);  // (E,D,F) -> (E,F,D)
  transpose_bf16_kernel<<<dim3(D_DIM / 64, F_DIM / 64, E_EXP), 256, 0, stream>>>(
      w2, w2t, F_DIM, D_DIM);  // (E,F,D) -> (E,D,F)

  // expert MLP
  gemm1_kernel<<<dim3(F_DIM / 128, CAPC / 128, E_EXP), 256, 0, stream>>>(
      xb, sel_idx, w1t, b1, H);
  gemm2_kernel<<<dim3(D_DIM / 128, CAPC / 128, E_EXP * 2), 256, 0, stream>>>(
      H, w2t, b2, P);

  // weighted combine back to token order (also zeroes dropped tokens)
  combine_kernel<<<T_TOK, 256, 0, stream>>>(P, inv_cnt, inv_ec, inv_w, y);
}